// Round 21
// baseline (27.831 us; speedup 1.0000x reference)
//
#include <hip/hip_runtime.h>

// ROUND 21: SPLITK=4 (drow = 4 float2 loads), reduce folded into triplet
// (64 line-private f64/u32 slots + done-counter finalize), R19 XCD mapping kept.

#define EPSF 1e-8f
#define MARGINF 0.5f
#define BN 512
#define DD 768
#define BT 64
#define SPLITK 4
#define KC (DD / SPLITK)   // 192
#define LPAD 200           // shorts/row = 100 dwords; frag-read rows collide 2-way max (free)
#define GBLK 256           // 4 z * 8 bi * 8 bj
#define NORMBLK 128

typedef __attribute__((ext_vector_type(8))) short bf16x8;
typedef __attribute__((ext_vector_type(4))) float f32x4;

__device__ __forceinline__ short f2bf(float f) {
    unsigned int u = __float_as_uint(f);
    return (short)((u + 0x7FFFu + ((u >> 16) & 1u)) >> 16);  // RNE
}

__device__ __forceinline__ bf16x8 pack8(const float4& a, const float4& b) {
    bf16x8 r;
    r[0] = f2bf(a.x); r[1] = f2bf(a.y); r[2] = f2bf(a.z); r[3] = f2bf(a.w);
    r[4] = f2bf(b.x); r[5] = f2bf(b.y); r[6] = f2bf(b.z); r[7] = f2bf(b.w);
    return r;
}

// ---------------- Node 1: gram partials SPLITK=4 (blocks 0..255) + norms (256..383) ----------------
__global__ __launch_bounds__(256) void prep_kernel(const float* __restrict__ x,
                                                   float* __restrict__ invn,
                                                   float* __restrict__ dotp) {
    int b = blockIdx.x;
    int t = threadIdx.x;
    int wv = t >> 6, lane = t & 63;

    if (b >= GBLK) {
        int row = (b - GBLK) * 4 + wv;
        float s = 0.f;
#pragma unroll
        for (int c = 0; c < 3; ++c) {
            float4 v = *(const float4*)&x[row * DD + (lane + c * 64) * 4];
            s += v.x * v.x + v.y * v.y + v.z * v.z + v.w * v.w;
        }
        for (int off = 32; off; off >>= 1) s += __shfl_down(s, off, 64);
        if (lane == 0) invn[row] = 1.0f / fmaxf(sqrtf(s), EPSF);
        return;
    }

    __shared__ __align__(16) short As[BT][LPAD];   // 25.6 KB
    __shared__ __align__(16) short Bs[BT][LPAD];   // 51.2 KB total -> 3 blocks/CU
    int bi = b & 7, bj = (b >> 3) & 7, bz = b >> 6;   // XCD-matched: row-group = b%8
    int i0 = bi * BT, j0 = bj * BT, kbase = bz * KC;

    {
        int row = t >> 2, fq = t & 3;
        const float* ap = &x[(i0 + row) * DD + kbase + fq * 8];
        const float* bp = &x[(j0 + row) * DD + kbase + fq * 8];
#pragma unroll
        for (int cc = 0; cc < 6; ++cc) {
            float4 a0 = *(const float4*)(ap + cc * 32);
            float4 a1 = *(const float4*)(ap + cc * 32 + 4);
            float4 b0 = *(const float4*)(bp + cc * 32);
            float4 b1 = *(const float4*)(bp + cc * 32 + 4);
            *(bf16x8*)&As[row][fq * 8 + cc * 32] = pack8(a0, a1);
            *(bf16x8*)&Bs[row][fq * 8 + cc * 32] = pack8(b0, b1);
        }
    }
    __syncthreads();

    int r16 = lane & 15;
    int kb8 = (lane >> 4) * 8;

    f32x4 accf[4];
#pragma unroll
    for (int c = 0; c < 4; ++c) accf[c] = (f32x4){0.f, 0.f, 0.f, 0.f};

#pragma unroll
    for (int s = 0; s < 6; ++s) {
        bf16x8 af = *(const bf16x8*)&As[wv * 16 + r16][kb8 + s * 32];
#pragma unroll
        for (int c = 0; c < 4; ++c) {
            bf16x8 bf_ = *(const bf16x8*)&Bs[c * 16 + r16][kb8 + s * 32];
            accf[c] = __builtin_amdgcn_mfma_f32_16x16x32_bf16(af, bf_, accf[c], 0, 0, 0);
        }
    }

    // C/D layout: col = lane&15, row = (lane>>4)*4 + reg   [verified R6-R20]
    float* o = dotp + (size_t)bz * BN * BN;
    int crow = i0 + wv * 16 + (lane >> 4) * 4;
#pragma unroll
    for (int c = 0; c < 4; ++c) {
        int ccol = j0 + c * 16 + r16;
#pragma unroll
        for (int r = 0; r < 4; ++r)
            o[(crow + r) * BN + ccol] = accf[c][r];
    }
}

// ---------------- Node 2: triplet + folded finalize ----------------
// accb: 64 slots x 64 B ({f64 sum, u32 cnt}); <=8 blocks RMW per line.
__global__ __launch_bounds__(256) void triplet_kernel(const float* __restrict__ dotp,
                                                      const float* __restrict__ invn,
                                                      const int* __restrict__ labels,
                                                      char* __restrict__ accb,
                                                      unsigned int* __restrict__ ctr,
                                                      float* __restrict__ out) {
    int r_ = blockIdx.x;
    int i = ((r_ & 7) << 6) | (r_ >> 3);   // XCD-matched anchor (R19)
    int t = threadIdx.x;
    int w = t >> 6, lane = t & 63;
    __shared__ float drow[BN];
    __shared__ int lab[BN];
    __shared__ __align__(16) float dpos[528];
    __shared__ int wcnt[8];
    __shared__ int woff[9];
    __shared__ float redf[4];
    __shared__ unsigned int redc[4];
    __shared__ unsigned int lastflag;

    if (t == 0) lastflag = 0u;
    lab[t] = labels[t];
    lab[t + 256] = labels[t + 256];
    float inv_i = invn[i];
    {
        float2 iv = *(const float2*)&invn[2 * t];
        float s0 = 0.f, s1 = 0.f;
#pragma unroll
        for (int z = 0; z < SPLITK; ++z) {
            float2 p = *(const float2*)&dotp[(size_t)z * BN * BN + i * BN + 2 * t];
            s0 += p.x; s1 += p.y;
        }
        drow[2 * t]     = 1.0f - s0 * inv_i * iv.x;
        drow[2 * t + 1] = 1.0f - s1 * inv_i * iv.y;
    }
    __syncthreads();

    int li = lab[i];
    bool p0 = (lab[t] == li) && (t != i);
    bool p1 = (lab[t + 256] == li) && ((t + 256) != i);
    unsigned long long m0 = __ballot(p0);
    unsigned long long m1 = __ballot(p1);
    if (lane == 0) { wcnt[w] = __popcll(m0); wcnt[4 + w] = __popcll(m1); }
    __syncthreads();
    if (t == 0) {
        int s = 0;
#pragma unroll
        for (int q = 0; q < 8; ++q) { woff[q] = s; s += wcnt[q]; }
        woff[8] = s;
    }
    __syncthreads();
    unsigned long long lmask = (1ull << lane) - 1ull;
    if (p0) dpos[woff[w] + __popcll(m0 & lmask)] = drow[t] + MARGINF;
    if (p1) dpos[woff[4 + w] + __popcll(m1 & lmask)] = drow[t + 256] + MARGINF;
    int npos = woff[8];
    int npad = (npos + 15) & ~15;
    if (t < npad - npos) dpos[npos + t] = -1e30f;
    __syncthreads();

    float dk0 = (lab[t] != li) ? drow[t] : 1e30f;
    float dk1 = (lab[t + 256] != li) ? drow[t + 256] : 1e30f;
    float sum = 0.f;
    unsigned int cnt = 0;
    for (int n = 0; n < npad; n += 16) {
        float4 q[4];
#pragma unroll
        for (int v = 0; v < 4; ++v) q[v] = *(const float4*)&dpos[n + v * 4];
#pragma unroll
        for (int v = 0; v < 4; ++v) {
            float bv[4] = {q[v].x, q[v].y, q[v].z, q[v].w};
#pragma unroll
            for (int u = 0; u < 4; ++u) {
                float v0 = bv[u] - dk0;
                float v1 = bv[u] - dk1;
                sum += fmaxf(v0, 0.f);
                if (v0 > EPSF) cnt++;
                sum += fmaxf(v1, 0.f);
                if (v1 > EPSF) cnt++;
            }
        }
    }
    for (int off = 32; off; off >>= 1) {
        sum += __shfl_down(sum, off, 64);
        cnt += __shfl_down(cnt, off, 64);
    }
    if (lane == 0) { redf[w] = sum; redc[w] = cnt; }
    __syncthreads();
    if (t == 0) {
        float stot = redf[0] + redf[1] + redf[2] + redf[3];
        unsigned int ctot = redc[0] + redc[1] + redc[2] + redc[3];
        double* dslot = (double*)(accb + (size_t)(i & 63) * 64);
        unsigned int* cslot = (unsigned int*)(accb + (size_t)(i & 63) * 64 + 8);
        atomicAdd(dslot, (double)stot);
        atomicAdd(cslot, ctot);
        __threadfence();
        unsigned int old = atomicAdd(ctr, 1u);
        if (old == BN - 1) lastflag = 1u;
    }
    __syncthreads();
    if (lastflag && t < 64) {
        __threadfence();
        double s = atomicAdd((double*)(accb + (size_t)t * 64), 0.0);          // RMW read
        unsigned int c = atomicAdd((unsigned int*)(accb + (size_t)t * 64 + 8), 0u);
        double cs = (double)c;
        for (int off = 32; off; off >>= 1) {
            s += __shfl_down(s, off, 64);
            cs += __shfl_down(cs, off, 64);
        }
        if (t == 0) out[0] = (float)(s / (cs + 1e-8));
    }
}

extern "C" void kernel_launch(void* const* d_in, const int* in_sizes, int n_in,
                              void* d_out, int out_size, void* d_ws, size_t ws_size,
                              hipStream_t stream) {
    const float* x = (const float*)d_in[0];
    const int* labels = (const int*)d_in[1];
    float* out = (float*)d_out;

    char* ws = (char*)d_ws;
    unsigned int* ctr = (unsigned int*)(ws + 64);   // 4 B
    char* accb = ws + 4096;                         // 64 slots x 64 B
    float* invn = (float*)(ws + 8192);              // 2 KB
    float* dotp = (float*)(ws + 16384);             // 4 MB

    hipMemsetAsync(ws, 0, 8192, stream);            // zero ctr + slots
    prep_kernel<<<GBLK + NORMBLK, 256, 0, stream>>>(x, invn, dotp);
    triplet_kernel<<<BN, 256, 0, stream>>>(dotp, invn, labels, accb, ctr, out);
}

// Round 22
// 18.066 us; speedup vs baseline: 1.5405x; 1.5405x over previous
//
#include <hip/hip_runtime.h>

// ROUND 22 = ROUND 19 (17.44 us best) reverted, + drow phase reads dotp as
// float2 (8 vector loads instead of 16 scalar). No memset node, no atomics.

#define EPSF 1e-8f
#define MARGINF 0.5f
#define BN 512
#define DD 768
#define BT 64
#define SPLITK 8
#define KC (DD / SPLITK)  // 96
#define LPAD 104          // shorts per LDS row: 52 dwords, 52%32=20 -> <=2-way on frag reads
#define NORMBLK 128

typedef __attribute__((ext_vector_type(8))) short bf16x8;
typedef __attribute__((ext_vector_type(4))) float f32x4;

__device__ __forceinline__ short f2bf(float f) {
    unsigned int u = __float_as_uint(f);
    return (short)((u + 0x7FFFu + ((u >> 16) & 1u)) >> 16);  // RNE
}

__device__ __forceinline__ bf16x8 pack8(const float4& a, const float4& b) {
    bf16x8 r;
    r[0] = f2bf(a.x); r[1] = f2bf(a.y); r[2] = f2bf(a.z); r[3] = f2bf(a.w);
    r[4] = f2bf(b.x); r[5] = f2bf(b.y); r[6] = f2bf(b.z); r[7] = f2bf(b.w);
    return r;
}

// ---------------- Node 1: MFMA gram partials (blocks 0..511, XCD-matched) + norms ----------------
__global__ __launch_bounds__(256) void prep_kernel(const float* __restrict__ x,
                                                   float* __restrict__ invn,
                                                   float* __restrict__ dotp) {
    int b = blockIdx.x;
    int t = threadIdx.x;
    int wv = t >> 6, lane = t & 63;

    if (b >= BN) {
        int row = (b - BN) * 4 + wv;
        float s = 0.f;
#pragma unroll
        for (int c = 0; c < 3; ++c) {
            float4 v = *(const float4*)&x[row * DD + (lane + c * 64) * 4];
            s += v.x * v.x + v.y * v.y + v.z * v.z + v.w * v.w;
        }
        for (int off = 32; off; off >>= 1) s += __shfl_down(s, off, 64);
        if (lane == 0) invn[row] = 1.0f / fmaxf(sqrtf(s), EPSF);
        return;
    }

    __shared__ __align__(16) short As[BT][LPAD];
    __shared__ __align__(16) short Bs[BT][LPAD];
    // XCD-matched decode: row-group bi == b % 8 == this block's XCD
    int bi = b & 7, bj = (b >> 3) & 7, bz = b >> 6;
    int i0 = bi * BT, j0 = bj * BT, kbase = bz * KC;

    {
        int row = t >> 2, fq = t & 3;
        const float* ap = &x[(i0 + row) * DD + kbase + fq * 8];
        const float* bp = &x[(j0 + row) * DD + kbase + fq * 8];
#pragma unroll
        for (int cc = 0; cc < 3; ++cc) {
            float4 a0 = *(const float4*)(ap + cc * 32);
            float4 a1 = *(const float4*)(ap + cc * 32 + 4);
            float4 b0 = *(const float4*)(bp + cc * 32);
            float4 b1 = *(const float4*)(bp + cc * 32 + 4);
            *(bf16x8*)&As[row][fq * 8 + cc * 32] = pack8(a0, a1);
            *(bf16x8*)&Bs[row][fq * 8 + cc * 32] = pack8(b0, b1);
        }
    }
    __syncthreads();

    int r16 = lane & 15;
    int kb8 = (lane >> 4) * 8;

    f32x4 accf[4];
#pragma unroll
    for (int c = 0; c < 4; ++c) accf[c] = (f32x4){0.f, 0.f, 0.f, 0.f};

#pragma unroll
    for (int s = 0; s < 3; ++s) {
        bf16x8 af = *(const bf16x8*)&As[wv * 16 + r16][kb8 + s * 32];
#pragma unroll
        for (int c = 0; c < 4; ++c) {
            bf16x8 bf_ = *(const bf16x8*)&Bs[c * 16 + r16][kb8 + s * 32];
            accf[c] = __builtin_amdgcn_mfma_f32_16x16x32_bf16(af, bf_, accf[c], 0, 0, 0);
        }
    }

    // C/D layout: col = lane&15, row = (lane>>4)*4 + reg   [verified R6-R21]
    float* o = dotp + (size_t)bz * BN * BN;
    int crow = i0 + wv * 16 + (lane >> 4) * 4;
#pragma unroll
    for (int c = 0; c < 4; ++c) {
        int ccol = j0 + c * 16 + r16;
#pragma unroll
        for (int r = 0; r < 4; ++r)
            o[(crow + r) * BN + ccol] = accf[c][r];
    }
}

// ---------------- Node 2: triplet — XCD-matched anchor swizzle, float2 drow loads ----------------
__global__ __launch_bounds__(256) void triplet_kernel(const float* __restrict__ dotp,
                                                      const float* __restrict__ invn,
                                                      const int* __restrict__ labels,
                                                      float* __restrict__ psum,
                                                      unsigned int* __restrict__ pcnt) {
    int r_ = blockIdx.x;
    int i = ((r_ & 7) << 6) | (r_ >> 3);   // anchor: this block's XCD == writers' XCD
    int t = threadIdx.x;
    int w = t >> 6, lane = t & 63;
    __shared__ float drow[BN];
    __shared__ int lab[BN];
    __shared__ __align__(16) float dpos[528];
    __shared__ int wcnt[8];
    __shared__ int woff[9];
    __shared__ float redf[4];
    __shared__ unsigned int redc[4];

    lab[t] = labels[t];
    lab[t + 256] = labels[t + 256];
    float inv_i = invn[i];
    {
        float2 iv = *(const float2*)&invn[2 * t];
        float s0 = 0.f, s1 = 0.f;
#pragma unroll
        for (int z = 0; z < SPLITK; ++z) {
            float2 p = *(const float2*)&dotp[(size_t)z * BN * BN + i * BN + 2 * t];
            s0 += p.x; s1 += p.y;
        }
        drow[2 * t]     = 1.0f - s0 * inv_i * iv.x;
        drow[2 * t + 1] = 1.0f - s1 * inv_i * iv.y;
    }
    __syncthreads();

    int li = lab[i];
    bool p0 = (lab[t] == li) && (t != i);
    bool p1 = (lab[t + 256] == li) && ((t + 256) != i);
    unsigned long long m0 = __ballot(p0);
    unsigned long long m1 = __ballot(p1);
    if (lane == 0) { wcnt[w] = __popcll(m0); wcnt[4 + w] = __popcll(m1); }
    __syncthreads();
    if (t == 0) {
        int s = 0;
#pragma unroll
        for (int q = 0; q < 8; ++q) { woff[q] = s; s += wcnt[q]; }
        woff[8] = s;
    }
    __syncthreads();
    unsigned long long lmask = (1ull << lane) - 1ull;
    if (p0) dpos[woff[w] + __popcll(m0 & lmask)] = drow[t] + MARGINF;
    if (p1) dpos[woff[4 + w] + __popcll(m1 & lmask)] = drow[t + 256] + MARGINF;
    int npos = woff[8];
    int npad = (npos + 15) & ~15;
    if (t < npad - npos) dpos[npos + t] = -1e30f;
    __syncthreads();

    float dk0 = (lab[t] != li) ? drow[t] : 1e30f;
    float dk1 = (lab[t + 256] != li) ? drow[t + 256] : 1e30f;
    float sum = 0.f;
    unsigned int cnt = 0;
    for (int n = 0; n < npad; n += 16) {
        float4 q[4];
#pragma unroll
        for (int v = 0; v < 4; ++v) q[v] = *(const float4*)&dpos[n + v * 4];
#pragma unroll
        for (int v = 0; v < 4; ++v) {
            float bv[4] = {q[v].x, q[v].y, q[v].z, q[v].w};
#pragma unroll
            for (int u = 0; u < 4; ++u) {
                float v0 = bv[u] - dk0;
                float v1 = bv[u] - dk1;
                sum += fmaxf(v0, 0.f);
                if (v0 > EPSF) cnt++;
                sum += fmaxf(v1, 0.f);
                if (v1 > EPSF) cnt++;
            }
        }
    }
    for (int off = 32; off; off >>= 1) {
        sum += __shfl_down(sum, off, 64);
        cnt += __shfl_down(cnt, off, 64);
    }
    if (lane == 0) { redf[w] = sum; redc[w] = cnt; }
    __syncthreads();
    if (t == 0) {
        psum[i] = redf[0] + redf[1] + redf[2] + redf[3];
        pcnt[i] = redc[0] + redc[1] + redc[2] + redc[3];
    }
}

// ---------------- Node 3: final reduce (1 block, deterministic) ----------------
__global__ __launch_bounds__(256) void reduce_kernel(const float* __restrict__ psum,
                                                     const unsigned int* __restrict__ pcnt,
                                                     float* __restrict__ out) {
    int t = threadIdx.x;
    double s = (double)psum[t] + (double)psum[t + 256];
    double c = (double)pcnt[t] + (double)pcnt[t + 256];
    for (int off = 32; off; off >>= 1) {
        s += __shfl_down(s, off, 64);
        c += __shfl_down(c, off, 64);
    }
    __shared__ double sred[4], cred[4];
    if ((t & 63) == 0) { sred[t >> 6] = s; cred[t >> 6] = c; }
    __syncthreads();
    if (t == 0) {
        double stot = sred[0] + sred[1] + sred[2] + sred[3];
        double ctot = cred[0] + cred[1] + cred[2] + cred[3];
        out[0] = (float)(stot / (ctot + 1e-8));
    }
}

extern "C" void kernel_launch(void* const* d_in, const int* in_sizes, int n_in,
                              void* d_out, int out_size, void* d_ws, size_t ws_size,
                              hipStream_t stream) {
    const float* x = (const float*)d_in[0];
    const int* labels = (const int*)d_in[1];
    float* out = (float*)d_out;

    char* ws = (char*)d_ws;
    float* invn = (float*)(ws + 256);               // 2 KB
    float* psum = (float*)(ws + 4096);              // 2 KB
    unsigned int* pcnt = (unsigned int*)(ws + 8192);// 2 KB
    float* dotp = (float*)(ws + 16384);             // 8 MB

    prep_kernel<<<BN + NORMBLK, 256, 0, stream>>>(x, invn, dotp);
    triplet_kernel<<<BN, 256, 0, stream>>>(dotp, invn, labels, psum, pcnt);
    reduce_kernel<<<1, 256, 0, stream>>>(psum, pcnt, out);
}

// Round 23
// 17.831 us; speedup vs baseline: 1.5609x; 1.0132x over previous
//
#include <hip/hip_runtime.h>

// ROUND 23 = ROUND 19 verbatim (best measured: 17.44 us).
// prep: split-K=8 MFMA gram, XCD-matched decode (row-group = b%8) + norms.
// triplet: XCD-matched anchor swizzle, compact positive list, branchless b128 loop.
// reduce: 1-block deterministic f64 reduce.

#define EPSF 1e-8f
#define MARGINF 0.5f
#define BN 512
#define DD 768
#define BT 64
#define SPLITK 8
#define KC (DD / SPLITK)  // 96
#define LPAD 104          // shorts per LDS row: 52 dwords, 52%32=20 -> <=2-way on frag reads
#define NORMBLK 128

typedef __attribute__((ext_vector_type(8))) short bf16x8;
typedef __attribute__((ext_vector_type(4))) float f32x4;

__device__ __forceinline__ short f2bf(float f) {
    unsigned int u = __float_as_uint(f);
    return (short)((u + 0x7FFFu + ((u >> 16) & 1u)) >> 16);  // RNE
}

__device__ __forceinline__ bf16x8 pack8(const float4& a, const float4& b) {
    bf16x8 r;
    r[0] = f2bf(a.x); r[1] = f2bf(a.y); r[2] = f2bf(a.z); r[3] = f2bf(a.w);
    r[4] = f2bf(b.x); r[5] = f2bf(b.y); r[6] = f2bf(b.z); r[7] = f2bf(b.w);
    return r;
}

// ---------------- Node 1: MFMA gram partials (blocks 0..511) + norms (512..639) ----------------
__global__ __launch_bounds__(256) void prep_kernel(const float* __restrict__ x,
                                                   float* __restrict__ invn,
                                                   float* __restrict__ dotp) {
    int b = blockIdx.x;
    int t = threadIdx.x;
    int wv = t >> 6, lane = t & 63;

    if (b >= BN) {
        int row = (b - BN) * 4 + wv;
        float s = 0.f;
#pragma unroll
        for (int c = 0; c < 3; ++c) {
            float4 v = *(const float4*)&x[row * DD + (lane + c * 64) * 4];
            s += v.x * v.x + v.y * v.y + v.z * v.z + v.w * v.w;
        }
        for (int off = 32; off; off >>= 1) s += __shfl_down(s, off, 64);
        if (lane == 0) invn[row] = 1.0f / fmaxf(sqrtf(s), EPSF);
        return;
    }

    __shared__ __align__(16) short As[BT][LPAD];
    __shared__ __align__(16) short Bs[BT][LPAD];
    // XCD-matched decode: row-group bi == b % 8 == this block's XCD
    int bi = b & 7, bj = (b >> 3) & 7, bz = b >> 6;
    int i0 = bi * BT, j0 = bj * BT, kbase = bz * KC;

    {
        int row = t >> 2, fq = t & 3;
        const float* ap = &x[(i0 + row) * DD + kbase + fq * 8];
        const float* bp = &x[(j0 + row) * DD + kbase + fq * 8];
#pragma unroll
        for (int cc = 0; cc < 3; ++cc) {
            float4 a0 = *(const float4*)(ap + cc * 32);
            float4 a1 = *(const float4*)(ap + cc * 32 + 4);
            float4 b0 = *(const float4*)(bp + cc * 32);
            float4 b1 = *(const float4*)(bp + cc * 32 + 4);
            *(bf16x8*)&As[row][fq * 8 + cc * 32] = pack8(a0, a1);
            *(bf16x8*)&Bs[row][fq * 8 + cc * 32] = pack8(b0, b1);
        }
    }
    __syncthreads();

    int r16 = lane & 15;
    int kb8 = (lane >> 4) * 8;

    f32x4 accf[4];
#pragma unroll
    for (int c = 0; c < 4; ++c) accf[c] = (f32x4){0.f, 0.f, 0.f, 0.f};

#pragma unroll
    for (int s = 0; s < 3; ++s) {
        bf16x8 af = *(const bf16x8*)&As[wv * 16 + r16][kb8 + s * 32];
#pragma unroll
        for (int c = 0; c < 4; ++c) {
            bf16x8 bf_ = *(const bf16x8*)&Bs[c * 16 + r16][kb8 + s * 32];
            accf[c] = __builtin_amdgcn_mfma_f32_16x16x32_bf16(af, bf_, accf[c], 0, 0, 0);
        }
    }

    // C/D layout: col = lane&15, row = (lane>>4)*4 + reg   [verified R6-R22]
    float* o = dotp + (size_t)bz * BN * BN;
    int crow = i0 + wv * 16 + (lane >> 4) * 4;
#pragma unroll
    for (int c = 0; c < 4; ++c) {
        int ccol = j0 + c * 16 + r16;
#pragma unroll
        for (int r = 0; r < 4; ++r)
            o[(crow + r) * BN + ccol] = accf[c][r];
    }
}

// ---------------- Node 2: triplet — XCD-matched anchor swizzle ----------------
__global__ __launch_bounds__(256) void triplet_kernel(const float* __restrict__ dotp,
                                                      const float* __restrict__ invn,
                                                      const int* __restrict__ labels,
                                                      float* __restrict__ psum,
                                                      unsigned int* __restrict__ pcnt) {
    int r_ = blockIdx.x;
    int i = ((r_ & 7) << 6) | (r_ >> 3);   // anchor: this block's XCD == writers' XCD
    int t = threadIdx.x;
    int w = t >> 6, lane = t & 63;
    __shared__ float drow[BN];
    __shared__ int lab[BN];
    __shared__ __align__(16) float dpos[528];
    __shared__ int wcnt[8];
    __shared__ int woff[9];
    __shared__ float redf[4];
    __shared__ unsigned int redc[4];

    lab[t] = labels[t];
    lab[t + 256] = labels[t + 256];
    float inv_i = invn[i];
#pragma unroll
    for (int e0 = 0; e0 < BN; e0 += 256) {
        int e = e0 + t;
        float s = 0.f;
#pragma unroll
        for (int z = 0; z < SPLITK; ++z) s += dotp[(size_t)z * BN * BN + i * BN + e];
        drow[e] = 1.0f - s * inv_i * invn[e];
    }
    __syncthreads();

    int li = lab[i];
    bool p0 = (lab[t] == li) && (t != i);
    bool p1 = (lab[t + 256] == li) && ((t + 256) != i);
    unsigned long long m0 = __ballot(p0);
    unsigned long long m1 = __ballot(p1);
    if (lane == 0) { wcnt[w] = __popcll(m0); wcnt[4 + w] = __popcll(m1); }
    __syncthreads();
    if (t == 0) {
        int s = 0;
#pragma unroll
        for (int q = 0; q < 8; ++q) { woff[q] = s; s += wcnt[q]; }
        woff[8] = s;
    }
    __syncthreads();
    unsigned long long lmask = (1ull << lane) - 1ull;
    if (p0) dpos[woff[w] + __popcll(m0 & lmask)] = drow[t] + MARGINF;
    if (p1) dpos[woff[4 + w] + __popcll(m1 & lmask)] = drow[t + 256] + MARGINF;
    int npos = woff[8];
    int npad = (npos + 15) & ~15;
    if (t < npad - npos) dpos[npos + t] = -1e30f;
    __syncthreads();

    float dk0 = (lab[t] != li) ? drow[t] : 1e30f;
    float dk1 = (lab[t + 256] != li) ? drow[t + 256] : 1e30f;
    float sum = 0.f;
    unsigned int cnt = 0;
    for (int n = 0; n < npad; n += 16) {
        float4 q[4];
#pragma unroll
        for (int v = 0; v < 4; ++v) q[v] = *(const float4*)&dpos[n + v * 4];
#pragma unroll
        for (int v = 0; v < 4; ++v) {
            float bv[4] = {q[v].x, q[v].y, q[v].z, q[v].w};
#pragma unroll
            for (int u = 0; u < 4; ++u) {
                float v0 = bv[u] - dk0;
                float v1 = bv[u] - dk1;
                sum += fmaxf(v0, 0.f);
                if (v0 > EPSF) cnt++;
                sum += fmaxf(v1, 0.f);
                if (v1 > EPSF) cnt++;
            }
        }
    }
    for (int off = 32; off; off >>= 1) {
        sum += __shfl_down(sum, off, 64);
        cnt += __shfl_down(cnt, off, 64);
    }
    if (lane == 0) { redf[w] = sum; redc[w] = cnt; }
    __syncthreads();
    if (t == 0) {
        psum[i] = redf[0] + redf[1] + redf[2] + redf[3];
        pcnt[i] = redc[0] + redc[1] + redc[2] + redc[3];
    }
}

// ---------------- Node 3: final reduce (1 block, deterministic) ----------------
__global__ __launch_bounds__(256) void reduce_kernel(const float* __restrict__ psum,
                                                     const unsigned int* __restrict__ pcnt,
                                                     float* __restrict__ out) {
    int t = threadIdx.x;
    double s = (double)psum[t] + (double)psum[t + 256];
    double c = (double)pcnt[t] + (double)pcnt[t + 256];
    for (int off = 32; off; off >>= 1) {
        s += __shfl_down(s, off, 64);
        c += __shfl_down(c, off, 64);
    }
    __shared__ double sred[4], cred[4];
    if ((t & 63) == 0) { sred[t >> 6] = s; cred[t >> 6] = c; }
    __syncthreads();
    if (t == 0) {
        double stot = sred[0] + sred[1] + sred[2] + sred[3];
        double ctot = cred[0] + cred[1] + cred[2] + cred[3];
        out[0] = (float)(stot / (ctot + 1e-8));
    }
}

extern "C" void kernel_launch(void* const* d_in, const int* in_sizes, int n_in,
                              void* d_out, int out_size, void* d_ws, size_t ws_size,
                              hipStream_t stream) {
    const float* x = (const float*)d_in[0];
    const int* labels = (const int*)d_in[1];
    float* out = (float*)d_out;

    char* ws = (char*)d_ws;
    float* invn = (float*)(ws + 256);               // 2 KB
    float* psum = (float*)(ws + 4096);              // 2 KB
    unsigned int* pcnt = (unsigned int*)(ws + 8192);// 2 KB
    float* dotp = (float*)(ws + 16384);             // 8 MB

    prep_kernel<<<BN + NORMBLK, 256, 0, stream>>>(x, invn, dotp);
    triplet_kernel<<<BN, 256, 0, stream>>>(dotp, invn, labels, psum, pcnt);
    reduce_kernel<<<1, 256, 0, stream>>>(psum, pcnt, out);
}